// Round 2
// baseline (564.928 us; speedup 1.0000x reference)
//
#include <hip/hip_runtime.h>
#include <math.h>

#define H 4096
#define E 64
#define BK 32
#define BM 64
#define TOPK 8

// Fused router: f64-accumulated logits GEMM + bias + sigmoid + in-block top-8.
// Block: 256 threads -> 64 rows x 64 experts (full expert dim in-block, so
// top-k can run on exact f64 logits without a second kernel / workspace).
// f64 accumulation: the harness checks indices against a float64 numpy
// reference; f32 accumulation (~1e-6 logit error) flips near-tied ranks.
__global__ __launch_bounds__(256) void router_fused_kernel(
    const float* __restrict__ A, const float* __restrict__ Wm,
    const float* __restrict__ bias, float* __restrict__ weights,
    float* __restrict__ indices, float* __restrict__ probs)
{
    __shared__ float  Alds[BM][BK + 4];  // +4 pad, keeps 16B alignment
    __shared__ float  Wlds[BK][E];       // k-major
    __shared__ double Llds[BM][E + 1];   // f64 logits for top-k (+1 pad)

    const int tid  = threadIdx.x;
    const int er   = tid & 15;      // experts [4*er, 4*er+4)
    const int rr   = tid >> 4;      // rows    [4*rr, 4*rr+4)
    const int lrow = tid >> 3;      // staging row/expert 0..31
    const int seg  = tid & 7;       // staging 16B segment

    const long row0 = (long)blockIdx.x * BM;

    double acc[4][4];
#pragma unroll
    for (int i = 0; i < 4; ++i)
#pragma unroll
        for (int j = 0; j < 4; ++j) acc[i][j] = 0.0;

    // --- register prefetch of tile 0 ---
    float4 pa0 = *(const float4*)(A + (row0 + lrow) * H + seg * 4);
    float4 pa1 = *(const float4*)(A + (row0 + lrow + 32) * H + seg * 4);
    float4 pw0 = *(const float4*)(Wm + (long)lrow * H + seg * 4);
    float4 pw1 = *(const float4*)(Wm + (long)(lrow + 32) * H + seg * 4);

    for (int k0 = 0; k0 < H; k0 += BK) {
        // write prefetched tile to LDS
        *(float4*)&Alds[lrow][seg * 4]      = pa0;
        *(float4*)&Alds[lrow + 32][seg * 4] = pa1;
        Wlds[seg * 4 + 0][lrow] = pw0.x;
        Wlds[seg * 4 + 1][lrow] = pw0.y;
        Wlds[seg * 4 + 2][lrow] = pw0.z;
        Wlds[seg * 4 + 3][lrow] = pw0.w;
        Wlds[seg * 4 + 0][lrow + 32] = pw1.x;
        Wlds[seg * 4 + 1][lrow + 32] = pw1.y;
        Wlds[seg * 4 + 2][lrow + 32] = pw1.z;
        Wlds[seg * 4 + 3][lrow + 32] = pw1.w;
        __syncthreads();

        // issue loads for next tile; they stay in flight during the dfma block
        if (k0 + BK < H) {
            const int kn = k0 + BK;
            pa0 = *(const float4*)(A + (row0 + lrow) * H + kn + seg * 4);
            pa1 = *(const float4*)(A + (row0 + lrow + 32) * H + kn + seg * 4);
            pw0 = *(const float4*)(Wm + (long)lrow * H + kn + seg * 4);
            pw1 = *(const float4*)(Wm + (long)(lrow + 32) * H + kn + seg * 4);
        }

#pragma unroll
        for (int kk = 0; kk < BK; kk += 4) {
            double a[4][4];   // [row i][k m]
            double w[4][4];   // [k m][expert j]
#pragma unroll
            for (int i = 0; i < 4; ++i) {
                const float4 t = *(const float4*)&Alds[rr * 4 + i][kk];
                a[i][0] = (double)t.x; a[i][1] = (double)t.y;
                a[i][2] = (double)t.z; a[i][3] = (double)t.w;
            }
#pragma unroll
            for (int m = 0; m < 4; ++m) {
                const float4 t = *(const float4*)&Wlds[kk + m][er * 4];
                w[m][0] = (double)t.x; w[m][1] = (double)t.y;
                w[m][2] = (double)t.z; w[m][3] = (double)t.w;
            }
#pragma unroll
            for (int m = 0; m < 4; ++m)
#pragma unroll
                for (int i = 0; i < 4; ++i)
#pragma unroll
                    for (int j = 0; j < 4; ++j)
                        acc[i][j] = fma(a[i][m], w[m][j], acc[i][j]);
        }
        __syncthreads();
    }

    // --- epilogue: bias, stash f64 logits in LDS, write f32 probs ---
    const float4 bv = *(const float4*)(bias + er * 4);
    const double bb[4] = {(double)bv.x, (double)bv.y, (double)bv.z, (double)bv.w};
#pragma unroll
    for (int i = 0; i < 4; ++i) {
        float4 o;
        float* op = (float*)&o;
#pragma unroll
        for (int j = 0; j < 4; ++j) {
            const double lg = acc[i][j] + bb[j];
            Llds[rr * 4 + i][er * 4 + j] = lg;
            op[j] = 1.0f / (1.0f + __expf(-(float)lg));
        }
        *(float4*)(probs + (row0 + rr * 4 + i) * E + er * 4) = o;
    }
    __syncthreads();

    // --- top-8 on exact f64 logits: thread r handles row r ---
    if (tid < BM) {
        const int r = tid;
        unsigned long long taken = 0ull;
        float wsel[TOPK];
        int   isel[TOPK];
        float sum = 0.0f;
#pragma unroll
        for (int it = 0; it < TOPK; ++it) {
            double best = -1.0e300;
            int    bi   = 0;
            for (int j = 0; j < E; ++j) {
                if (!((taken >> j) & 1ull)) {
                    const double v = Llds[r][j];
                    if (v > best) { best = v; bi = j; }  // strict > => lowest idx on tie
                }
            }
            taken |= (1ull << bi);
            const float p = 1.0f / (1.0f + __expf(-(float)best));
            wsel[it] = p;
            isel[it] = bi;
            sum += p;
        }
        const float inv = 1.0f / sum;
#pragma unroll
        for (int it = 0; it < TOPK; ++it) {
            weights[(row0 + r) * TOPK + it] = wsel[it] * inv;
            indices[(row0 + r) * TOPK + it] = (float)isel[it];
        }
    }
}

extern "C" void kernel_launch(void* const* d_in, const int* in_sizes, int n_in,
                              void* d_out, int out_size, void* d_ws, size_t ws_size,
                              hipStream_t stream) {
    const float* A    = (const float*)d_in[0];   // [T, H]
    const float* W    = (const float*)d_in[1];   // [E, H]
    const float* bias = (const float*)d_in[2];   // [E]
    const int T = in_sizes[0] / H;               // 16384

    float* out     = (float*)d_out;
    float* weights = out;                          // [T, 8]
    float* indices = out + (size_t)T * TOPK;       // [T, 8] (float-valued)
    float* probs   = out + (size_t)T * 2 * TOPK;   // [T, 64]

    hipLaunchKernelGGL(router_fused_kernel, dim3(T / BM), dim3(256), 0, stream,
                       A, W, bias, weights, indices, probs);
}